// Round 2
// baseline (645.337 us; speedup 1.0000x reference)
//
#include <hip/hip_runtime.h>

// TxGNN R8: collapse msg_mfma's phase structure.
// R7 profile: msg still ~83us each vs ~27us HBM floor; all utilizations low
// => per-block phase-latency bound (6 phases / 4 barriers).
// R8: A-fragments read DIRECTLY from ea_s (identity LDS copy had exactly one
// consumer per byte; direct load is perfectly coalesced 16B/lane). B-fragments
// read directly from WbotT (16KB, L1-resident across all 10000 blocks). Ms no
// longer aliases staging => acc->Ms needs no preceding barrier. 4 syncs -> 2.
// Numerically bit-identical to R7. Also: 4 wconv launches fused into 1.

constexpr int N_NODES = 50000;
constexpr int N_EDGES = 640000;
constexpr int DF = 128;
constexpr int DE = 64;

typedef short bf16x8 __attribute__((ext_vector_type(8)));
typedef float f32x4 __attribute__((ext_vector_type(4)));

__device__ __forceinline__ void fatomic(float* p, float v) {
#if defined(__AMDGCN__)
    unsafeAtomicAdd(p, v);
#else
    atomicAdd(p, v);
#endif
}

__device__ __forceinline__ unsigned short f2bf(float f) {
    union { float f; unsigned u; } v; v.f = f;
    unsigned r = (v.u + 0x7FFFu + ((v.u >> 16) & 1u)) >> 16;
    return (unsigned short)r;
}
__device__ __forceinline__ float b2f(unsigned short u) {
    union { unsigned u; float f; } v; v.u = (unsigned)u << 16;
    return v.f;
}

// ---------------------------------------------------------------------------
// All four weight transposes in one launch.
// Segments: Wm1(192x128) Wa1(256x128) Wm2(192x128) Wa2(256x128)
__global__ __launch_bounds__(256)
void wconv4_kernel(const float* __restrict__ W0, unsigned short* __restrict__ T0,
                   const float* __restrict__ W1, unsigned short* __restrict__ T1,
                   const float* __restrict__ W2, unsigned short* __restrict__ T2,
                   const float* __restrict__ W3, unsigned short* __restrict__ T3) {
    int i = blockIdx.x * blockDim.x + threadIdx.x;
    const float* W; unsigned short* T; int K;
    if (i < 24576)      { W = W0; T = T0; K = 192; }
    else if (i < 57344) { W = W1; T = T1; K = 256; i -= 24576; }
    else if (i < 81920) { W = W2; T = T2; K = 192; i -= 57344; }
    else if (i < 114688){ W = W3; T = T3; K = 256; i -= 81920; }
    else return;
    int k = i >> 7, n = i & 127;
    T[n * K + k] = f2bf(W[k * 128 + n]);
}

// CSR build: histogram -> 3-kernel scan -> permutation scatter.
__global__ __launch_bounds__(256)
void hist_kernel(const int* __restrict__ dst, int* __restrict__ hist) {
    int i = blockIdx.x * blockDim.x + threadIdx.x;
    if (i < N_EDGES) atomicAdd(&hist[dst[i]], 1);
}

__global__ __launch_bounds__(256)
void scan1_kernel(const int* __restrict__ hist, int* __restrict__ excl,
                  int* __restrict__ blksum, int n) {
    __shared__ int buf[256];
    const int t = threadIdx.x;
    const int i = blockIdx.x * 256 + t;
    int v = (i < n) ? hist[i] : 0;
    buf[t] = v;
    __syncthreads();
    #pragma unroll
    for (int off = 1; off < 256; off <<= 1) {
        int x = (t >= off) ? buf[t - off] : 0;
        __syncthreads();
        buf[t] += x;
        __syncthreads();
    }
    if (i < n) excl[i] = buf[t] - v;
    if (t == 255) blksum[blockIdx.x] = buf[255];
}

__global__ __launch_bounds__(256)
void scan2_kernel(int* __restrict__ blksum, int nb) {
    __shared__ int buf[256];
    const int t = threadIdx.x;
    int v = (t < nb) ? blksum[t] : 0;
    buf[t] = v;
    __syncthreads();
    #pragma unroll
    for (int off = 1; off < 256; off <<= 1) {
        int x = (t >= off) ? buf[t - off] : 0;
        __syncthreads();
        buf[t] += x;
        __syncthreads();
    }
    if (t < nb) blksum[t] = buf[t] - v;
}

__global__ __launch_bounds__(256)
void scan3_kernel(int* __restrict__ excl, const int* __restrict__ blksum, int n) {
    const int i = blockIdx.x * 256 + threadIdx.x;
    if (i < n) excl[i] += blksum[blockIdx.x];
}

__global__ __launch_bounds__(256)
void build_kernel(const int* __restrict__ src, const int* __restrict__ dst,
                  int* __restrict__ cursor,
                  int* __restrict__ perm, int* __restrict__ srcs,
                  int* __restrict__ dsts) {
    int e = blockIdx.x * blockDim.x + threadIdx.x;
    if (e < N_EDGES) {
        const int d = dst[e];
        const int pos = atomicAdd(&cursor[d], 1);
        perm[pos] = e;
        srcs[pos] = src[e];
        dsts[pos] = d;
    }
}

// ea_s[p] = bf16(ea[perm[p]]) — sorted, streaming-friendly, reused 2x.
__global__ __launch_bounds__(256)
void ea_sort_kernel(const float* __restrict__ ea, const int* __restrict__ perm,
                    unsigned short* __restrict__ ea_s) {
    const int t = threadIdx.x;
    const int p = blockIdx.x * 16 + (t >> 4);
    const int c = (t & 15) * 4;
    const int e = perm[p];
    float4 f = *(const float4*)(ea + (size_t)e * DE + c);
    ushort4 o;
    o.x = f2bf(f.x); o.y = f2bf(f.y); o.z = f2bf(f.z); o.w = f2bf(f.w);
    *(ushort4*)(ea_s + (size_t)p * DE + c) = o;
}

// ---------------------------------------------------------------------------
// MFMA row GEMM: C[i,:] = act( cat(A1[i],A2[i]) @ W + bias ), N=128 wide.
// OUTBF: write bf16 (for xw) else fp32.
// ---------------------------------------------------------------------------
template<int K1, int K2, bool RELU, bool BIAS, bool OUTBF>
__global__ __launch_bounds__(256)
void gemm_mfma(const float* __restrict__ A1,
               const float* __restrict__ A2,
               const unsigned short* __restrict__ WT, int wstride,
               const float* __restrict__ bias,
               void* __restrict__ Cv, int n)
{
    constexpr int K = K1 + K2;
    __shared__ unsigned short Asm[64][72];
    __shared__ unsigned short Bsm[128][72];

    const int r0   = blockIdx.x * 64;
    const int t    = threadIdx.x;
    const int wave = t >> 6;
    const int lane = t & 63;
    const int quad = lane >> 4;
    const int l15  = lane & 15;

    f32x4 acc[8];
    #pragma unroll
    for (int ct = 0; ct < 8; ++ct) acc[ct] = (f32x4)(0.f);

    const int arow  = t >> 2;
    const int acol0 = (t & 3) * 16;
    int arowg = r0 + arow; if (arowg >= n) arowg = n - 1;
    const int brow = t >> 1;
    const int bk   = (t & 1) * 32;

    for (int k0 = 0; k0 < K; k0 += 64) {
        {
            const int col = k0 + acol0;
            const float* sp = (K2 == 0 || col < K1)
                ? A1 + (size_t)arowg * K1 + col
                : A2 + (size_t)arowg * K2 + (col - K1);
            union { unsigned short us[16]; uint4 q[2]; } tmp;
            #pragma unroll
            for (int u = 0; u < 4; ++u) {
                float4 f = *(const float4*)(sp + u * 4);
                tmp.us[u * 4 + 0] = f2bf(f.x);
                tmp.us[u * 4 + 1] = f2bf(f.y);
                tmp.us[u * 4 + 2] = f2bf(f.z);
                tmp.us[u * 4 + 3] = f2bf(f.w);
            }
            *(uint4*)&Asm[arow][acol0]     = tmp.q[0];
            *(uint4*)&Asm[arow][acol0 + 8] = tmp.q[1];
        }
        {
            const unsigned short* bp = WT + (size_t)brow * wstride + k0 + bk;
            uint4 b0 = *(const uint4*)(bp);
            uint4 b1 = *(const uint4*)(bp + 8);
            uint4 b2 = *(const uint4*)(bp + 16);
            uint4 b3 = *(const uint4*)(bp + 24);
            *(uint4*)&Bsm[brow][bk]      = b0;
            *(uint4*)&Bsm[brow][bk + 8]  = b1;
            *(uint4*)&Bsm[brow][bk + 16] = b2;
            *(uint4*)&Bsm[brow][bk + 24] = b3;
        }
        __syncthreads();
        #pragma unroll
        for (int kh = 0; kh < 2; ++kh) {
            bf16x8 a = *(const bf16x8*)&Asm[wave * 16 + l15][kh * 32 + quad * 8];
            #pragma unroll
            for (int ct = 0; ct < 8; ++ct) {
                bf16x8 b = *(const bf16x8*)&Bsm[ct * 16 + l15][kh * 32 + quad * 8];
                acc[ct] = __builtin_amdgcn_mfma_f32_16x16x32_bf16(a, b, acc[ct], 0, 0, 0);
            }
        }
        __syncthreads();
    }

    #pragma unroll
    for (int ct = 0; ct < 8; ++ct) {
        const int col = ct * 16 + l15;
        const float bval = BIAS ? bias[col] : 0.f;
        #pragma unroll
        for (int reg = 0; reg < 4; ++reg) {
            const int row = r0 + wave * 16 + quad * 4 + reg;
            if (row < n) {
                float v = acc[ct][reg] + bval;
                if (RELU) v = v > 0.f ? v : 0.f;
                if (OUTBF) ((unsigned short*)Cv)[(size_t)row * 128 + col] = f2bf(v);
                else       ((float*)Cv)[(size_t)row * 128 + col] = v;
            }
        }
    }
}

// ---------------------------------------------------------------------------
// Edge message (MFMA, direct-operand) + parallel LDS segment-reduce scatter.
//   m[p] = relu( xw[srcs[p]] + ea_s[p] @ Wbot + bias ); aggr[dsts[p]] += m
// A-fragments: direct from ea_s (coalesced, single consumer per byte).
// B-fragments: direct from WbotT (16KB, L1-resident across all blocks).
// Only 2 barriers: after acc->Ms, after add+relu.
// ---------------------------------------------------------------------------
__global__ __launch_bounds__(256, 4)
void msg_mfma(const unsigned short* __restrict__ xwb,   // [N,128] bf16
              const unsigned short* __restrict__ ea_s,  // [E,64] bf16 sorted
              const int*   __restrict__ srcs,
              const int*   __restrict__ dsts,
              const unsigned short* __restrict__ WbotT, // [128][wstride]
              int wstride,
              const float* __restrict__ bias,
              float* __restrict__ aggr)
{
    __shared__ float Ms[64][132];      // 33792 B
    __shared__ int Ds[64];
    __shared__ int Rstart[64];
    __shared__ int Meta[3];            // nruns, dprev, dnext

    const int p0   = blockIdx.x * 64;
    const int t    = threadIdx.x;
    const int wave = t >> 6;
    const int lane = t & 63;
    const int quad = lane >> 4;
    const int l15  = lane & 15;
    const int tx   = t & 31;
    const int ty   = t >> 5;

    // ---- run-head detection (wave 0, overlaps everything up to sync 2) ----
    if (t < 64) {
        const int d  = dsts[p0 + t];
        const int dl = __shfl_up(d, 1);
        const bool head = (t == 0) || (d != dl);
        const unsigned long long mask = __ballot(head);
        const int idx = __popcll(mask & ((1ull << t) - 1ull));
        if (head) Rstart[idx] = t;
        if (t == 0) {
            Meta[0] = (int)__popcll(mask);
            Meta[1] = (p0 == 0) ? -1 : dsts[p0 - 1];
        }
        if (t == 1) Meta[2] = (p0 + 64 >= N_EDGES) ? -1 : dsts[p0 + 64];
        Ds[t] = d;
    }

    // ---- prefetch xw[src] rows (bf16, 8B/thread/row, coalesced 256B) ----
    const int pbase = p0 + ty * 8;
    ushort4 xv[8];
    #pragma unroll
    for (int r = 0; r < 8; ++r) {
        const int s = srcs[pbase + r];
        xv[r] = *(const ushort4*)(xwb + (size_t)s * 128 + tx * 4);
    }

    // ---- A-fragments direct from ea_s (identical indices to old Asm) ----
    const unsigned short* ap = ea_s + (size_t)(p0 + wave * 16 + l15) * DE + quad * 8;
    bf16x8 a0 = *(const bf16x8*)(ap);
    bf16x8 a1 = *(const bf16x8*)(ap + 32);

    // ---- MFMA, B-fragments direct from WbotT (L1-hot) ----
    f32x4 acc[8];
    #pragma unroll
    for (int ct = 0; ct < 8; ++ct) {
        const unsigned short* bp = WbotT + (size_t)(ct * 16 + l15) * wstride + quad * 8;
        bf16x8 b0 = *(const bf16x8*)(bp);
        bf16x8 b1 = *(const bf16x8*)(bp + 32);
        acc[ct] = __builtin_amdgcn_mfma_f32_16x16x32_bf16(a0, b0, (f32x4)(0.f), 0, 0, 0);
        acc[ct] = __builtin_amdgcn_mfma_f32_16x16x32_bf16(a1, b1, acc[ct], 0, 0, 0);
    }

    // ---- acc -> Ms (edge-major fp32); Ms aliases nothing, no barrier needed
    #pragma unroll
    for (int ct = 0; ct < 8; ++ct)
        #pragma unroll
        for (int reg = 0; reg < 4; ++reg)
            Ms[wave * 16 + quad * 4 + reg][ct * 16 + l15] = acc[ct][reg];
    __syncthreads();

    // ---- add xw + bias, relu, in place ----
    float bv[4];
    *(float4*)bv = *(const float4*)(bias + tx * 4);
    #pragma unroll
    for (int r = 0; r < 8; ++r) {
        float4 m = *(float4*)&Ms[ty * 8 + r][tx * 4];
        float v0 = m.x + b2f(xv[r].x) + bv[0];
        float v1 = m.y + b2f(xv[r].y) + bv[1];
        float v2 = m.z + b2f(xv[r].z) + bv[2];
        float v3 = m.w + b2f(xv[r].w) + bv[3];
        m.x = v0 > 0.f ? v0 : 0.f;
        m.y = v1 > 0.f ? v1 : 0.f;
        m.z = v2 > 0.f ? v2 : 0.f;
        m.w = v3 > 0.f ? v3 : 0.f;
        *(float4*)&Ms[ty * 8 + r][tx * 4] = m;
    }
    __syncthreads();

    // ---- all-thread segment reduce: (run x colgroup) work items ----
    {
        const int nr    = Meta[0];
        const int dprev = Meta[1];
        const int dnext = Meta[2];
        const int g4    = tx * 4;
        for (int run = t >> 5; run < nr; run += 8) {
            const int start = Rstart[run];
            const int end   = (run + 1 < nr) ? Rstart[run + 1] : 64;
            const int d     = Ds[start];
            float4 s = *(float4*)&Ms[start][g4];
            for (int r = start + 1; r < end; ++r) {
                float4 v = *(float4*)&Ms[r][g4];
                s.x += v.x; s.y += v.y; s.z += v.z; s.w += v.w;
            }
            float* ap2 = aggr + (size_t)d * 128 + g4;
            if ((start == 0 && d == dprev) || (end == 64 && d == dnext)) {
                fatomic(ap2 + 0, s.x); fatomic(ap2 + 1, s.y);
                fatomic(ap2 + 2, s.z); fatomic(ap2 + 3, s.w);
            } else {
                *(float4*)ap2 = s;
            }
        }
    }
}

// ---------------------------------------------------------------------------
extern "C" void kernel_launch(void* const* d_in, const int* in_sizes, int n_in,
                              void* d_out, int out_size, void* d_ws, size_t ws_size,
                              hipStream_t stream) {
    const float* x    = (const float*)d_in[0];
    const int*   eidx = (const int*)  d_in[1];
    const float* ea   = (const float*)d_in[2];
    const float* Wm1  = (const float*)d_in[3];
    const float* bm1  = (const float*)d_in[4];
    const float* Wa1  = (const float*)d_in[5];
    const float* ba1  = (const float*)d_in[6];
    const float* Wm2  = (const float*)d_in[7];
    const float* bm2  = (const float*)d_in[8];
    const float* Wa2  = (const float*)d_in[9];
    const float* ba2  = (const float*)d_in[10];
    float* out = (float*)d_out;

    const int* src = eidx;
    const int* dst = eidx + N_EDGES;

    const size_t nodeBuf = (size_t)N_NODES * DF;
    float* aggr = (float*)d_ws;                                // 25.6 MB
    unsigned short* xwb  = (unsigned short*)(aggr + nodeBuf);  // 12.8 MB
    unsigned short* ea_s = xwb + nodeBuf;                      // 81.9 MB
    int* cursor = (int*)(ea_s + (size_t)N_EDGES * DE);
    int* perm   = cursor + N_NODES;
    int* srcs   = perm + N_EDGES;
    int* dsts   = srcs + N_EDGES;
    unsigned short* WmT1 = (unsigned short*)(dsts + N_EDGES);  // [128][192]
    unsigned short* WaT1 = WmT1 + 128 * 192;                   // [128][256]
    unsigned short* WmT2 = WaT1 + 128 * 256;
    unsigned short* WaT2 = WmT2 + 128 * 192;
    int* blksum = (int*)(WaT2 + 128 * 256);
    float* h = out;   // layer-1 output scratch lives in d_out (overwritten)

    const int gN = (N_NODES + 63) / 64;       // 782
    const int gE = N_EDGES / 64;              // 10000
    const int gS = (N_NODES + 255) / 256;     // 196
    dim3 blk(256);

    // ---- weights: transpose + bf16 (one fused launch) ----
    wconv4_kernel<<<(114688 + 255) / 256, blk, 0, stream>>>(
        Wm1, WmT1, Wa1, WaT1, Wm2, WmT2, Wa2, WaT2);

    // ---- CSR permutation + sorted bf16 edge features ----
    hipMemsetAsync(dsts, 0, N_NODES * sizeof(int), stream);    // hist scratch
    hist_kernel<<<(N_EDGES + 255) / 256, blk, 0, stream>>>(dst, dsts);
    scan1_kernel<<<gS, blk, 0, stream>>>(dsts, cursor, blksum, N_NODES);
    scan2_kernel<<<1, blk, 0, stream>>>(blksum, gS);
    scan3_kernel<<<gS, blk, 0, stream>>>(cursor, blksum, N_NODES);
    build_kernel<<<(N_EDGES + 255) / 256, blk, 0, stream>>>(
        src, dst, cursor, perm, srcs, dsts);
    ea_sort_kernel<<<N_EDGES / 16, blk, 0, stream>>>(ea, perm, ea_s);

    // ---- layer 1 ----
    hipMemsetAsync(aggr, 0, nodeBuf * sizeof(float), stream);
    gemm_mfma<DF, 0, false, false, true><<<gN, blk, 0, stream>>>(
        x, nullptr, WmT1, 192, nullptr, xwb, N_NODES);         // xwb = bf16(x@Wm1_top)
    msg_mfma<<<gE, blk, 0, stream>>>(
        xwb, ea_s, srcs, dsts, WmT1 + 128, 192, bm1, aggr);
    gemm_mfma<DF, DF, true, true, false><<<gN, blk, 0, stream>>>(
        aggr, x, WaT1, 256, ba1, h, N_NODES);

    // ---- layer 2 ----
    hipMemsetAsync(aggr, 0, nodeBuf * sizeof(float), stream);
    gemm_mfma<DF, 0, false, false, true><<<gN, blk, 0, stream>>>(
        h, nullptr, WmT2, 192, nullptr, xwb, N_NODES);
    msg_mfma<<<gE, blk, 0, stream>>>(
        xwb, ea_s, srcs, dsts, WmT2 + 128, 192, bm2, aggr);
    gemm_mfma<DF, DF, true, true, false><<<gN, blk, 0, stream>>>(
        aggr, h, WaT2, 256, ba2, out, N_NODES);
}

// Round 3
// 563.303 us; speedup vs baseline: 1.1456x; 1.1456x over previous
//
#include <hip/hip_runtime.h>

// TxGNN R9: R8's 2-barrier msg structure + fragment-linear B.
// R8 regressed msg 83->107us: the direct B-fragment gather from WbotT was
// wave-scattered (16 rows x 384B stride per instr, 16 instrs/thread, re-read
// by all 10000 blocks over a 48KB span) -> L1 transaction serialization.
// R9 precomputes Bf[((ct*2+kh)*64+lane)*8+e] once (16KB dense, L1-hot):
// every B fragment load is base+lane*16B, one coalesced 1KB wave-instr.
// Values bit-identical. Keeps: direct-A from ea_s, 2 barriers, parallel
// segment-reduce epilogue, fused wconv.

constexpr int N_NODES = 50000;
constexpr int N_EDGES = 640000;
constexpr int DF = 128;
constexpr int DE = 64;

typedef short bf16x8 __attribute__((ext_vector_type(8)));
typedef float f32x4 __attribute__((ext_vector_type(4)));

__device__ __forceinline__ void fatomic(float* p, float v) {
#if defined(__AMDGCN__)
    unsafeAtomicAdd(p, v);
#else
    atomicAdd(p, v);
#endif
}

__device__ __forceinline__ unsigned short f2bf(float f) {
    union { float f; unsigned u; } v; v.f = f;
    unsigned r = (v.u + 0x7FFFu + ((v.u >> 16) & 1u)) >> 16;
    return (unsigned short)r;
}
__device__ __forceinline__ float b2f(unsigned short u) {
    union { unsigned u; float f; } v; v.u = (unsigned)u << 16;
    return v.f;
}

// ---------------------------------------------------------------------------
// One launch: 4 weight transposes (for gemm) + 2 fragment-linear msg weights.
// Segments: Wm1(192x128) Wa1(256x128) Wm2(192x128) Wa2(256x128) Bf1 Bf2
__global__ __launch_bounds__(256)
void wconv_kernel(const float* __restrict__ W0, unsigned short* __restrict__ T0,
                  const float* __restrict__ W1, unsigned short* __restrict__ T1,
                  const float* __restrict__ W2, unsigned short* __restrict__ T2,
                  const float* __restrict__ W3, unsigned short* __restrict__ T3,
                  unsigned short* __restrict__ Bf1,
                  unsigned short* __restrict__ Bf2) {
    int i = blockIdx.x * blockDim.x + threadIdx.x;
    if (i < 114688) {
        const float* W; unsigned short* T; int K;
        if (i < 24576)      { W = W0; T = T0; K = 192; }
        else if (i < 57344) { W = W1; T = T1; K = 256; i -= 24576; }
        else if (i < 81920) { W = W2; T = T2; K = 192; i -= 57344; }
        else                { W = W3; T = T3; K = 256; i -= 81920; }
        int k = i >> 7, n = i & 127;
        T[n * K + k] = f2bf(W[k * 128 + n]);
    } else if (i < 131072) {
        int j = i - 114688;
        const int w = j >> 13;           // 0 -> layer1, 1 -> layer2
        j &= 8191;
        const float* W = w ? W2 : W0;    // Wm2 : Wm1 (original [192][128])
        unsigned short* T = w ? Bf2 : Bf1;
        const int e    = j & 7;
        const int lane = (j >> 3) & 63;
        const int ctkh = j >> 9;         // ct*2+kh
        const int ct   = ctkh >> 1;
        const int kh   = ctkh & 1;
        const int l15  = lane & 15;
        const int quad = lane >> 4;
        const int k = 128 + kh * 32 + quad * 8 + e;   // bottom-half K index
        const int n = ct * 16 + l15;                  // output column
        T[j] = f2bf(W[k * 128 + n]);
    }
}

// CSR build: histogram -> 3-kernel scan -> permutation scatter.
__global__ __launch_bounds__(256)
void hist_kernel(const int* __restrict__ dst, int* __restrict__ hist) {
    int i = blockIdx.x * blockDim.x + threadIdx.x;
    if (i < N_EDGES) atomicAdd(&hist[dst[i]], 1);
}

__global__ __launch_bounds__(256)
void scan1_kernel(const int* __restrict__ hist, int* __restrict__ excl,
                  int* __restrict__ blksum, int n) {
    __shared__ int buf[256];
    const int t = threadIdx.x;
    const int i = blockIdx.x * 256 + t;
    int v = (i < n) ? hist[i] : 0;
    buf[t] = v;
    __syncthreads();
    #pragma unroll
    for (int off = 1; off < 256; off <<= 1) {
        int x = (t >= off) ? buf[t - off] : 0;
        __syncthreads();
        buf[t] += x;
        __syncthreads();
    }
    if (i < n) excl[i] = buf[t] - v;
    if (t == 255) blksum[blockIdx.x] = buf[255];
}

__global__ __launch_bounds__(256)
void scan2_kernel(int* __restrict__ blksum, int nb) {
    __shared__ int buf[256];
    const int t = threadIdx.x;
    int v = (t < nb) ? blksum[t] : 0;
    buf[t] = v;
    __syncthreads();
    #pragma unroll
    for (int off = 1; off < 256; off <<= 1) {
        int x = (t >= off) ? buf[t - off] : 0;
        __syncthreads();
        buf[t] += x;
        __syncthreads();
    }
    if (t < nb) blksum[t] = buf[t] - v;
}

__global__ __launch_bounds__(256)
void scan3_kernel(int* __restrict__ excl, const int* __restrict__ blksum, int n) {
    const int i = blockIdx.x * 256 + threadIdx.x;
    if (i < n) excl[i] += blksum[blockIdx.x];
}

__global__ __launch_bounds__(256)
void build_kernel(const int* __restrict__ src, const int* __restrict__ dst,
                  int* __restrict__ cursor,
                  int* __restrict__ perm, int* __restrict__ srcs,
                  int* __restrict__ dsts) {
    int e = blockIdx.x * blockDim.x + threadIdx.x;
    if (e < N_EDGES) {
        const int d = dst[e];
        const int pos = atomicAdd(&cursor[d], 1);
        perm[pos] = e;
        srcs[pos] = src[e];
        dsts[pos] = d;
    }
}

// ea_s[p] = bf16(ea[perm[p]]) — sorted, streaming-friendly, reused 2x.
__global__ __launch_bounds__(256)
void ea_sort_kernel(const float* __restrict__ ea, const int* __restrict__ perm,
                    unsigned short* __restrict__ ea_s) {
    const int t = threadIdx.x;
    const int p = blockIdx.x * 16 + (t >> 4);
    const int c = (t & 15) * 4;
    const int e = perm[p];
    float4 f = *(const float4*)(ea + (size_t)e * DE + c);
    ushort4 o;
    o.x = f2bf(f.x); o.y = f2bf(f.y); o.z = f2bf(f.z); o.w = f2bf(f.w);
    *(ushort4*)(ea_s + (size_t)p * DE + c) = o;
}

// ---------------------------------------------------------------------------
// MFMA row GEMM: C[i,:] = act( cat(A1[i],A2[i]) @ W + bias ), N=128 wide.
// OUTBF: write bf16 (for xw) else fp32.
// ---------------------------------------------------------------------------
template<int K1, int K2, bool RELU, bool BIAS, bool OUTBF>
__global__ __launch_bounds__(256)
void gemm_mfma(const float* __restrict__ A1,
               const float* __restrict__ A2,
               const unsigned short* __restrict__ WT, int wstride,
               const float* __restrict__ bias,
               void* __restrict__ Cv, int n)
{
    constexpr int K = K1 + K2;
    __shared__ unsigned short Asm[64][72];
    __shared__ unsigned short Bsm[128][72];

    const int r0   = blockIdx.x * 64;
    const int t    = threadIdx.x;
    const int wave = t >> 6;
    const int lane = t & 63;
    const int quad = lane >> 4;
    const int l15  = lane & 15;

    f32x4 acc[8];
    #pragma unroll
    for (int ct = 0; ct < 8; ++ct) acc[ct] = (f32x4)(0.f);

    const int arow  = t >> 2;
    const int acol0 = (t & 3) * 16;
    int arowg = r0 + arow; if (arowg >= n) arowg = n - 1;
    const int brow = t >> 1;
    const int bk   = (t & 1) * 32;

    for (int k0 = 0; k0 < K; k0 += 64) {
        {
            const int col = k0 + acol0;
            const float* sp = (K2 == 0 || col < K1)
                ? A1 + (size_t)arowg * K1 + col
                : A2 + (size_t)arowg * K2 + (col - K1);
            union { unsigned short us[16]; uint4 q[2]; } tmp;
            #pragma unroll
            for (int u = 0; u < 4; ++u) {
                float4 f = *(const float4*)(sp + u * 4);
                tmp.us[u * 4 + 0] = f2bf(f.x);
                tmp.us[u * 4 + 1] = f2bf(f.y);
                tmp.us[u * 4 + 2] = f2bf(f.z);
                tmp.us[u * 4 + 3] = f2bf(f.w);
            }
            *(uint4*)&Asm[arow][acol0]     = tmp.q[0];
            *(uint4*)&Asm[arow][acol0 + 8] = tmp.q[1];
        }
        {
            const unsigned short* bp = WT + (size_t)brow * wstride + k0 + bk;
            uint4 b0 = *(const uint4*)(bp);
            uint4 b1 = *(const uint4*)(bp + 8);
            uint4 b2 = *(const uint4*)(bp + 16);
            uint4 b3 = *(const uint4*)(bp + 24);
            *(uint4*)&Bsm[brow][bk]      = b0;
            *(uint4*)&Bsm[brow][bk + 8]  = b1;
            *(uint4*)&Bsm[brow][bk + 16] = b2;
            *(uint4*)&Bsm[brow][bk + 24] = b3;
        }
        __syncthreads();
        #pragma unroll
        for (int kh = 0; kh < 2; ++kh) {
            bf16x8 a = *(const bf16x8*)&Asm[wave * 16 + l15][kh * 32 + quad * 8];
            #pragma unroll
            for (int ct = 0; ct < 8; ++ct) {
                bf16x8 b = *(const bf16x8*)&Bsm[ct * 16 + l15][kh * 32 + quad * 8];
                acc[ct] = __builtin_amdgcn_mfma_f32_16x16x32_bf16(a, b, acc[ct], 0, 0, 0);
            }
        }
        __syncthreads();
    }

    #pragma unroll
    for (int ct = 0; ct < 8; ++ct) {
        const int col = ct * 16 + l15;
        const float bval = BIAS ? bias[col] : 0.f;
        #pragma unroll
        for (int reg = 0; reg < 4; ++reg) {
            const int row = r0 + wave * 16 + quad * 4 + reg;
            if (row < n) {
                float v = acc[ct][reg] + bval;
                if (RELU) v = v > 0.f ? v : 0.f;
                if (OUTBF) ((unsigned short*)Cv)[(size_t)row * 128 + col] = f2bf(v);
                else       ((float*)Cv)[(size_t)row * 128 + col] = v;
            }
        }
    }
}

// ---------------------------------------------------------------------------
// Edge message (MFMA, direct operands) + parallel LDS segment-reduce scatter.
//   m[p] = relu( xw[srcs[p]] + ea_s[p] @ Wbot + bias ); aggr[dsts[p]] += m
// A: direct coalesced from ea_s. B: fragment-linear Bf (16KB, L1-hot,
// base + lane*16B per load). Only 2 barriers.
// ---------------------------------------------------------------------------
__global__ __launch_bounds__(256, 4)
void msg_mfma(const unsigned short* __restrict__ xwb,   // [N,128] bf16
              const unsigned short* __restrict__ ea_s,  // [E,64] bf16 sorted
              const int*   __restrict__ srcs,
              const int*   __restrict__ dsts,
              const unsigned short* __restrict__ Bf,    // [16][64] bf16x8 frags
              const float* __restrict__ bias,
              float* __restrict__ aggr)
{
    __shared__ float Ms[64][132];      // 33792 B
    __shared__ int Ds[64];
    __shared__ int Rstart[64];
    __shared__ int Meta[3];            // nruns, dprev, dnext

    const int p0   = blockIdx.x * 64;
    const int t    = threadIdx.x;
    const int wave = t >> 6;
    const int lane = t & 63;
    const int quad = lane >> 4;
    const int l15  = lane & 15;
    const int tx   = t & 31;
    const int ty   = t >> 5;

    // ---- run-head detection (wave 0, overlaps everything up to sync 2) ----
    if (t < 64) {
        const int d  = dsts[p0 + t];
        const int dl = __shfl_up(d, 1);
        const bool head = (t == 0) || (d != dl);
        const unsigned long long mask = __ballot(head);
        const int idx = __popcll(mask & ((1ull << t) - 1ull));
        if (head) Rstart[idx] = t;
        if (t == 0) {
            Meta[0] = (int)__popcll(mask);
            Meta[1] = (p0 == 0) ? -1 : dsts[p0 - 1];
        }
        if (t == 1) Meta[2] = (p0 + 64 >= N_EDGES) ? -1 : dsts[p0 + 64];
        Ds[t] = d;
    }

    // ---- prefetch xw[src] rows (bf16, 8B/thread/row, coalesced 256B) ----
    const int pbase = p0 + ty * 8;
    ushort4 xv[8];
    #pragma unroll
    for (int r = 0; r < 8; ++r) {
        const int s = srcs[pbase + r];
        xv[r] = *(const ushort4*)(xwb + (size_t)s * 128 + tx * 4);
    }

    // ---- A-fragments direct from ea_s ----
    const unsigned short* ap = ea_s + (size_t)(p0 + wave * 16 + l15) * DE + quad * 8;
    bf16x8 a0 = *(const bf16x8*)(ap);
    bf16x8 a1 = *(const bf16x8*)(ap + 32);

    // ---- MFMA, B fragment-linear (coalesced, L1-hot) ----
    const bf16x8* Bv = (const bf16x8*)Bf;
    f32x4 acc[8];
    #pragma unroll
    for (int ct = 0; ct < 8; ++ct) {
        bf16x8 b0 = Bv[(ct * 2 + 0) * 64 + lane];
        bf16x8 b1 = Bv[(ct * 2 + 1) * 64 + lane];
        acc[ct] = __builtin_amdgcn_mfma_f32_16x16x32_bf16(a0, b0, (f32x4)(0.f), 0, 0, 0);
        acc[ct] = __builtin_amdgcn_mfma_f32_16x16x32_bf16(a1, b1, acc[ct], 0, 0, 0);
    }

    // ---- acc -> Ms (edge-major fp32); Ms aliases nothing, no barrier needed
    #pragma unroll
    for (int ct = 0; ct < 8; ++ct)
        #pragma unroll
        for (int reg = 0; reg < 4; ++reg)
            Ms[wave * 16 + quad * 4 + reg][ct * 16 + l15] = acc[ct][reg];
    __syncthreads();

    // ---- add xw + bias, relu, in place ----
    float bv[4];
    *(float4*)bv = *(const float4*)(bias + tx * 4);
    #pragma unroll
    for (int r = 0; r < 8; ++r) {
        float4 m = *(float4*)&Ms[ty * 8 + r][tx * 4];
        float v0 = m.x + b2f(xv[r].x) + bv[0];
        float v1 = m.y + b2f(xv[r].y) + bv[1];
        float v2 = m.z + b2f(xv[r].z) + bv[2];
        float v3 = m.w + b2f(xv[r].w) + bv[3];
        m.x = v0 > 0.f ? v0 : 0.f;
        m.y = v1 > 0.f ? v1 : 0.f;
        m.z = v2 > 0.f ? v2 : 0.f;
        m.w = v3 > 0.f ? v3 : 0.f;
        *(float4*)&Ms[ty * 8 + r][tx * 4] = m;
    }
    __syncthreads();

    // ---- all-thread segment reduce: (run x colgroup) work items ----
    {
        const int nr    = Meta[0];
        const int dprev = Meta[1];
        const int dnext = Meta[2];
        const int g4    = tx * 4;
        for (int run = t >> 5; run < nr; run += 8) {
            const int start = Rstart[run];
            const int end   = (run + 1 < nr) ? Rstart[run + 1] : 64;
            const int d     = Ds[start];
            float4 s = *(float4*)&Ms[start][g4];
            for (int r = start + 1; r < end; ++r) {
                float4 v = *(float4*)&Ms[r][g4];
                s.x += v.x; s.y += v.y; s.z += v.z; s.w += v.w;
            }
            float* ap2 = aggr + (size_t)d * 128 + g4;
            if ((start == 0 && d == dprev) || (end == 64 && d == dnext)) {
                fatomic(ap2 + 0, s.x); fatomic(ap2 + 1, s.y);
                fatomic(ap2 + 2, s.z); fatomic(ap2 + 3, s.w);
            } else {
                *(float4*)ap2 = s;
            }
        }
    }
}

// ---------------------------------------------------------------------------
extern "C" void kernel_launch(void* const* d_in, const int* in_sizes, int n_in,
                              void* d_out, int out_size, void* d_ws, size_t ws_size,
                              hipStream_t stream) {
    const float* x    = (const float*)d_in[0];
    const int*   eidx = (const int*)  d_in[1];
    const float* ea   = (const float*)d_in[2];
    const float* Wm1  = (const float*)d_in[3];
    const float* bm1  = (const float*)d_in[4];
    const float* Wa1  = (const float*)d_in[5];
    const float* ba1  = (const float*)d_in[6];
    const float* Wm2  = (const float*)d_in[7];
    const float* bm2  = (const float*)d_in[8];
    const float* Wa2  = (const float*)d_in[9];
    const float* ba2  = (const float*)d_in[10];
    float* out = (float*)d_out;

    const int* src = eidx;
    const int* dst = eidx + N_EDGES;

    const size_t nodeBuf = (size_t)N_NODES * DF;
    float* aggr = (float*)d_ws;                                // 25.6 MB
    unsigned short* xwb  = (unsigned short*)(aggr + nodeBuf);  // 12.8 MB
    unsigned short* ea_s = xwb + nodeBuf;                      // 81.9 MB
    int* cursor = (int*)(ea_s + (size_t)N_EDGES * DE);
    int* perm   = cursor + N_NODES;
    int* srcs   = perm + N_EDGES;
    int* dsts   = srcs + N_EDGES;
    unsigned short* WmT1 = (unsigned short*)(dsts + N_EDGES);  // [128][192]
    unsigned short* WaT1 = WmT1 + 128 * 192;                   // [128][256]
    unsigned short* WmT2 = WaT1 + 128 * 256;
    unsigned short* WaT2 = WmT2 + 128 * 192;
    unsigned short* Bf1  = WaT2 + 128 * 256;                   // [8192] frag-linear
    unsigned short* Bf2  = Bf1 + 8192;
    int* blksum = (int*)(Bf2 + 8192);
    float* h = out;   // layer-1 output scratch lives in d_out (overwritten)

    const int gN = (N_NODES + 63) / 64;       // 782
    const int gE = N_EDGES / 64;              // 10000
    const int gS = (N_NODES + 255) / 256;     // 196
    dim3 blk(256);

    // ---- weights: transpose + bf16 + fragment-linear msg-B (one launch) ----
    wconv_kernel<<<131072 / 256, blk, 0, stream>>>(
        Wm1, WmT1, Wa1, WaT1, Wm2, WmT2, Wa2, WaT2, Bf1, Bf2);

    // ---- CSR permutation + sorted bf16 edge features ----
    hipMemsetAsync(dsts, 0, N_NODES * sizeof(int), stream);    // hist scratch
    hist_kernel<<<(N_EDGES + 255) / 256, blk, 0, stream>>>(dst, dsts);
    scan1_kernel<<<gS, blk, 0, stream>>>(dsts, cursor, blksum, N_NODES);
    scan2_kernel<<<1, blk, 0, stream>>>(blksum, gS);
    scan3_kernel<<<gS, blk, 0, stream>>>(cursor, blksum, N_NODES);
    build_kernel<<<(N_EDGES + 255) / 256, blk, 0, stream>>>(
        src, dst, cursor, perm, srcs, dsts);
    ea_sort_kernel<<<N_EDGES / 16, blk, 0, stream>>>(ea, perm, ea_s);

    // ---- layer 1 ----
    hipMemsetAsync(aggr, 0, nodeBuf * sizeof(float), stream);
    gemm_mfma<DF, 0, false, false, true><<<gN, blk, 0, stream>>>(
        x, nullptr, WmT1, 192, nullptr, xwb, N_NODES);         // xwb = bf16(x@Wm1_top)
    msg_mfma<<<gE, blk, 0, stream>>>(
        xwb, ea_s, srcs, dsts, Bf1, bm1, aggr);
    gemm_mfma<DF, DF, true, true, false><<<gN, blk, 0, stream>>>(
        aggr, x, WaT1, 256, ba1, h, N_NODES);

    // ---- layer 2 ----
    hipMemsetAsync(aggr, 0, nodeBuf * sizeof(float), stream);
    gemm_mfma<DF, 0, false, false, true><<<gN, blk, 0, stream>>>(
        h, nullptr, WmT2, 192, nullptr, xwb, N_NODES);
    msg_mfma<<<gE, blk, 0, stream>>>(
        xwb, ea_s, srcs, dsts, Bf2, bm2, aggr);
    gemm_mfma<DF, DF, true, true, false><<<gN, blk, 0, stream>>>(
        aggr, h, WaT2, 256, ba2, out, N_NODES);
}